// Round 7
// baseline (11629.375 us; speedup 1.0000x reference)
//
#include <hip/hip_runtime.h>
#include <math.h>

#define PI_F 3.14159265358979323846f
typedef unsigned long long u64;

// RK stage constants: beta[k], gdt[k]=GAMMA[k]*DT, mu[k]=0.5*DT*(ALPHA[k+1]-ALPHA[k])
__constant__ float c_beta[5] = {0.0f, -0.4178904745f, -1.192151694643f,
                                -1.697784692471f, -1.514183444257f};
__constant__ float c_gdt[5]  = {1.496590219993e-4f, 3.792103129999e-4f,
                                8.229550293869e-4f, 6.994504559488e-4f,
                                1.530572479681e-4f};
__constant__ float c_mu[5]   = {7.482951099965e-5f, 1.1037096768255e-4f,
                                1.2592740288505e-4f, 1.6801318377015e-4f,
                                2.08589346626e-5f};

struct __align__(128) Line { int v; int pad[31]; };

// Batched FFT workspace: up to 4 transforms side by side.
struct SharedMem {
  float sAr[1024], sAi[1024], sBr[1024], sBi[1024];  // [4][256] ping-pong
  float twr[128], twi[128];
  float t0r[645], t0i[645], t1r[645], t1i[645];      // [129][4] tiles, stride 5
};

// ---------------------------------------------------------------------------
// Coherent (L1-bypassing) 8B accessors for cross-block handoff arrays.
// Relaxed agent atomics: no wbL2/invL2 in their lowering.
// ---------------------------------------------------------------------------
__device__ __forceinline__ float2 ldc(const float2* p)
{
  u64 v = __hip_atomic_load((const u64*)p, __ATOMIC_RELAXED, __HIP_MEMORY_SCOPE_AGENT);
  float2 f; __builtin_memcpy(&f, &v, 8); return f;
}
__device__ __forceinline__ void stc(float2* p, float2 f)
{
  u64 v; __builtin_memcpy(&v, &f, 8);
  __hip_atomic_store((u64*)p, v, __ATOMIC_RELAXED, __HIP_MEMORY_SCOPE_AGENT);
}

// ---------------------------------------------------------------------------
// Fast group barrier: every block's wave 0 polls ALL n arrival lines
// directly (1/lane, relaxed) — no leader/release round-trip.
// ---------------------------------------------------------------------------
__device__ __forceinline__ void bar_all(Line* arr, int n, int idx, int gen)
{
  __syncthreads();
  if (threadIdx.x == 0)
    __hip_atomic_store(&arr[idx].v, gen, __ATOMIC_RELAXED, __HIP_MEMORY_SCOPE_AGENT);
  if (threadIdx.x < 64) {
    bool done = false;
    while (!done) {
      bool ok = true;
      for (int w = threadIdx.x; w < n; w += 64)
        if (__hip_atomic_load(&arr[w].v, __ATOMIC_RELAXED, __HIP_MEMORY_SCOPE_AGENT) < gen)
          ok = false;
      done = __all(ok);
      if (!done) __builtin_amdgcn_s_sleep(1);
    }
    __builtin_amdgcn_sched_barrier(0);
  }
  __syncthreads();
}

// Fenced leader-based barrier (registration + fallback path). As round 6.
__device__ __forceinline__ void bar_sync(Line* arr, Line* rel, int n, int idx,
                                         bool lead, int gen, bool fenced)
{
  const int t = threadIdx.x;
  __syncthreads();
  if (t == 0) {
    __builtin_amdgcn_s_waitcnt(0);
    __builtin_amdgcn_sched_barrier(0);
    if (fenced)
      __hip_atomic_store(&arr[idx].v, gen, __ATOMIC_RELEASE, __HIP_MEMORY_SCOPE_AGENT);
    else
      __hip_atomic_store(&arr[idx].v, gen, __ATOMIC_RELAXED, __HIP_MEMORY_SCOPE_AGENT);
  }
  if (lead && t < 64) {
    bool done = false;
    while (!done) {
      bool ok = true;
      for (int w = t; w < n; w += 64)
        if (__hip_atomic_load(&arr[w].v, __ATOMIC_RELAXED, __HIP_MEMORY_SCOPE_AGENT) < gen)
          ok = false;
      done = __all(ok);
      if (!done) __builtin_amdgcn_s_sleep(1);
    }
    __builtin_amdgcn_sched_barrier(0);
    if (fenced)
      (void)__hip_atomic_load(&arr[t & 7].v, __ATOMIC_ACQUIRE, __HIP_MEMORY_SCOPE_AGENT);
    if (t < 8) {
      if (fenced)
        __hip_atomic_store(&rel[t].v, gen, __ATOMIC_RELEASE, __HIP_MEMORY_SCOPE_AGENT);
      else
        __hip_atomic_store(&rel[t].v, gen, __ATOMIC_RELAXED, __HIP_MEMORY_SCOPE_AGENT);
    }
  }
  if (t == 0) {
    Line* f = &rel[idx & 7];
    while (__hip_atomic_load(&f->v, __ATOMIC_RELAXED, __HIP_MEMORY_SCOPE_AGENT) < gen)
      __builtin_amdgcn_s_sleep(1);
    if (fenced)
      (void)__hip_atomic_load(&f->v, __ATOMIC_ACQUIRE, __HIP_MEMORY_SCOPE_AGENT);
    __builtin_amdgcn_sched_barrier(0);
  }
  __syncthreads();
}

// ---------------------------------------------------------------------------
// Batched 256-point Stockham radix-2 FFT: B transforms side by side in LDS,
// one __syncthreads per stage covers all B. Result ends in sA. No scaling.
// ---------------------------------------------------------------------------
template<int B, bool INVERSE>
__device__ __forceinline__ void fftB(SharedMem& sh, int t)
{
  float *sr = sh.sAr, *si = sh.sAi, *dr = sh.sBr, *di = sh.sBi;
#pragma unroll
  for (int s = 0; s < 8; ++s) {
    __syncthreads();
    int m  = 1 << s;
    int k  = t & (m - 1);
    int jm = (t >> (s + 1)) << s;
    int i0 = k + jm;
    float wr = sh.twr[jm];
    float wi = INVERSE ? -sh.twi[jm] : sh.twi[jm];
    bool odd = (t >> s) & 1;
#pragma unroll
    for (int f = 0; f < B; ++f) {
      float c0r = sr[f * 256 + i0],       c0i = si[f * 256 + i0];
      float c1r = sr[f * 256 + i0 + 128], c1i = si[f * 256 + i0 + 128];
      float orr, oii;
      if (odd) {
        float xr = c0r - c1r, xi = c0i - c1i;
        orr = xr * wr - xi * wi;
        oii = xr * wi + xi * wr;
      } else {
        orr = c0r + c1r;
        oii = c0i + c1i;
      }
      dr[f * 256 + t] = orr; di[f * 256 + t] = oii;
    }
    float* tp;
    tp = sr; sr = dr; dr = tp;
    tp = si; si = di; di = tp;
  }
  __syncthreads();
}

// ---------------------------------------------------------------------------
// Layouts (float2). ky truncated to <=85 (dealias zeroes the rest forever).
//   u, h : [b][ky][kx]     8*129*256   (plain cached: same-block reuse)
//   G    : [f][b][ky][x]   4*8*129*256 (coherent handoff)
//   NL1  : [b][ky][x]      8*86*256    (coherent handoff)
//   rec  : [r][b][ky][kx]  3*8*129*256 (coherent; r=0 slab doubles as W1)
// ---------------------------------------------------------------------------

// real-space item: 4 x-columns. 3 batched FFT passes (4v, 4g, 2fwd).
__device__ __forceinline__ void real_item4(SharedMem& sh, int t, int b, int x0,
    const float2* __restrict__ G, float2* __restrict__ NL1)
{
  for (int i = t; i < 516; i += 256) {               // fields 0,1 tiles
    int ky = i >> 2, xl = i & 3;
    float ax = 0.f, ay = 0.f, cx = 0.f, cy = 0.f;
    if (ky <= 85) {
      float2 a = ldc(&G[(((size_t)0 * 8 + b) * 129 + ky) * 256 + x0 + xl]);
      float2 c = ldc(&G[(((size_t)1 * 8 + b) * 129 + ky) * 256 + x0 + xl]);
      ax = a.x; ay = a.y; cx = c.x; cy = c.y;
    }
    sh.t0r[ky * 5 + xl] = ax; sh.t0i[ky * 5 + xl] = ay;
    sh.t1r[ky * 5 + xl] = cx; sh.t1i[ky * 5 + xl] = cy;
  }
  __syncthreads();
  const int  kk    = (t <= 128) ? t : 256 - t;
  const bool lower = (t <= 128);
#pragma unroll
  for (int xl = 0; xl < 4; ++xl) {                   // Z = Hvx + i*Hvy
    float ar = sh.t0r[kk * 5 + xl], ai = sh.t0i[kk * 5 + xl];
    float br = sh.t1r[kk * 5 + xl], bi = sh.t1i[kk * 5 + xl];
    sh.sAr[xl * 256 + t] = lower ? (ar - bi) : (ar + bi);
    sh.sAi[xl * 256 + t] = lower ? (ai + br) : (br - ai);
  }
  fftB<4, true>(sh, t);
  float vxr[4], vyr[4];
#pragma unroll
  for (int xl = 0; xl < 4; ++xl) { vxr[xl] = sh.sAr[xl * 256 + t]; vyr[xl] = sh.sAi[xl * 256 + t]; }
  for (int i = t; i < 516; i += 256) {               // fields 2,3 tiles
    int ky = i >> 2, xl = i & 3;
    float ax = 0.f, ay = 0.f, cx = 0.f, cy = 0.f;
    if (ky <= 85) {
      float2 a = ldc(&G[(((size_t)2 * 8 + b) * 129 + ky) * 256 + x0 + xl]);
      float2 c = ldc(&G[(((size_t)3 * 8 + b) * 129 + ky) * 256 + x0 + xl]);
      ax = a.x; ay = a.y; cx = c.x; cy = c.y;
    }
    sh.t0r[ky * 5 + xl] = ax; sh.t0i[ky * 5 + xl] = ay;
    sh.t1r[ky * 5 + xl] = cx; sh.t1i[ky * 5 + xl] = cy;
  }
  __syncthreads();
  float nl[4];
#pragma unroll
  for (int xl = 0; xl < 4; ++xl) {                   // Z = Hgx + i*Hgy
    float ar = sh.t0r[kk * 5 + xl], ai = sh.t0i[kk * 5 + xl];
    float br = sh.t1r[kk * 5 + xl], bi = sh.t1i[kk * 5 + xl];
    sh.sAr[xl * 256 + t] = lower ? (ar - bi) : (ar + bi);
    sh.sAi[xl * 256 + t] = lower ? (ai + br) : (br - ai);
  }
  fftB<4, true>(sh, t);
#pragma unroll
  for (int xl = 0; xl < 4; ++xl)
    nl[xl] = -(vxr[xl] * sh.sAr[xl * 256 + t] + vyr[xl] * sh.sAi[xl * 256 + t]);
  // forward rfft of 4 real rows packed into 2 complex FFTs
  sh.sAr[t]       = nl[0]; sh.sAi[t]       = nl[1];
  sh.sAr[256 + t] = nl[2]; sh.sAi[256 + t] = nl[3];
  fftB<2, false>(sh, t);
  if (t <= 85) {
    int mI = (256 - t) & 255;
#pragma unroll
    for (int p = 0; p < 2; ++p) {
      float zr = sh.sAr[p * 256 + t],  zi = sh.sAi[p * 256 + t];
      float wr = sh.sAr[p * 256 + mI], wi = sh.sAi[p * 256 + mI];
      stc(&NL1[((size_t)b * 86 + t) * 256 + x0 + 2 * p],
          make_float2(0.5f * (zr + wr), 0.5f * (zi - wi)));
      stc(&NL1[((size_t)b * 86 + t) * 256 + x0 + 2 * p + 1],
          make_float2(0.5f * (zi + wi), 0.5f * (wr - zr)));
    }
  }
  __syncthreads();   // protect cross-lane sA reads before next item's staging
}

// spectral item: 2 ky rows (ky0, ky0+1; both <86). fwd batch-2 + 2x inverse batch-4.
__device__ __forceinline__ void spectral_item2(SharedMem& sh, int t, int b, int ky0,
    const float2* __restrict__ NL1, float2* __restrict__ u, float2* __restrict__ h,
    float2* __restrict__ G, float2* __restrict__ rec,
    float beta, float gdt, float mu, bool doUpdate, int recIdx)
{
  const int jx = (t < 128) ? t : t - 256;
  const float fjx = (float)jx;
  float ur[2], ui[2];
#pragma unroll
  for (int f = 0; f < 2; ++f) {
    float2 uu = u[((size_t)b * 129 + ky0 + f) * 256 + t];
    ur[f] = uu.x; ui[f] = uu.y;
  }

  if (doUpdate) {
#pragma unroll
    for (int f = 0; f < 2; ++f) {
      float2 nv = ldc(&NL1[((size_t)b * 86 + ky0 + f) * 256 + t]);
      sh.sAr[f * 256 + t] = nv.x; sh.sAi[f * 256 + t] = nv.y;
    }
    fftB<2, false>(sh, t);
#pragma unroll
    for (int f = 0; f < 2; ++f) {
      const int ky = ky0 + f;
      const size_t row = ((size_t)b * 129 + ky) * 256;
      float advr = 0.f, advi = 0.f;
      if (t < 85 || t >= 171) { advr = sh.sAr[f * 256 + t]; advi = sh.sAi[f * 256 + t]; }
      if (t == 0 && ky == 4) {                       // forcing f_hat
        float s_, c_;
        __sincosf(PI_F / 64.0f, &s_, &c_);
        advr -= 131072.0f * c_;
        advi -= 131072.0f * s_;
      }
      float hr = advr, hi = advi;
      if (beta != 0.0f) {
        float2 hh = h[row + t];
        hr += beta * hh.x; hi += beta * hh.y;
      }
      const float k2   = (float)(jx * jx + ky * ky);
      const float lin  = -0.001f * k2 - 0.1f;
      const float anum = 1.0f + mu * lin;
      const float invd = 1.0f / (1.0f - mu * lin);
      ur[f] = (ur[f] * anum + gdt * hr) * invd;
      ui[f] = (ui[f] * anum + gdt * hi) * invd;
      u[row + t] = make_float2(ur[f], ui[f]);
      h[row + t] = make_float2(hr, hi);
      if (recIdx >= 0)
        stc(&rec[((size_t)recIdx * 8 + b) * (129 * 256) + (size_t)ky * 256 + t],
            make_float2(ur[f], ui[f]));
    }
  }

  const float NRM = 1.0f / 65536.0f;
#pragma unroll
  for (int f = 0; f < 2; ++f) {                      // inverse: 4 fields of row f
    const int ky = ky0 + f;
    const float k2 = (float)(jx * jx + ky * ky);
    const float inv_lapnz = (k2 == 0.0f) ? 1.0f : (-1.0f / k2);
    const float urN = ur[f] * NRM, uiN = ui[f] * NRM;
    const float psr = -urN * inv_lapnz, psi_ = -uiN * inv_lapnz;
    const float fjy = (float)ky;
    sh.sAr[0 * 256 + t] = -fjy * psi_; sh.sAi[0 * 256 + t] =  fjy * psr;  // vx
    sh.sAr[1 * 256 + t] =  fjx * psi_; sh.sAi[1 * 256 + t] = -fjx * psr;  // vy
    sh.sAr[2 * 256 + t] = -fjx * uiN;  sh.sAi[2 * 256 + t] =  fjx * urN;  // gx
    sh.sAr[3 * 256 + t] = -fjy * uiN;  sh.sAi[3 * 256 + t] =  fjy * urN;  // gy
    fftB<4, true>(sh, t);
#pragma unroll
    for (int fd = 0; fd < 4; ++fd)
      stc(&G[(((size_t)fd * 8 + b) * 129 + ky) * 256 + t],
          make_float2(sh.sAr[fd * 256 + t], sh.sAi[fd * 256 + t]));
  }
}

// ---------------------------------------------------------------------------
// Persistent kernel. Blocks self-organize into 8 per-XCD groups (HW_REG_XCC_ID);
// group g serves batch g. Fast path: all-poll flag barriers + coherent data.
// Fallback: blockIdx grouping with fenced leader barriers.
// ---------------------------------------------------------------------------
__global__ __launch_bounds__(256, 4) void k_persist(
    const float* __restrict__ vort, float* __restrict__ out,
    float2* __restrict__ u, float2* __restrict__ h,
    float2* __restrict__ G, float2* __restrict__ NL1, float2* __restrict__ rec,
    Line* __restrict__ bar)
{
  const int t   = threadIdx.x;
  const int blk = blockIdx.x;
  const int NBg = gridDim.x;

  Line* arrGrid = bar;                    // 1024 lines
  Line* relGrid = bar + 1024;             // 8
  Line* arrGrpA = bar + 1032;             // 8 * 256
  Line* relGrpA = bar + 1032 + 2048;      // 8 * 8
  Line* regL    = bar + 1032 + 2048 + 64; // 16: per-XCD counters

  __shared__ SharedMem sh;
  __shared__ int s_x, s_wi;

  if (t < 128) {
    float s_, c_;
    __sincosf(-(2.0f * PI_F / 256.0f) * (float)t, &s_, &c_);
    sh.twr[t] = c_; sh.twi[t] = s_;
  }

  // ---- registration: claim a worker slot on this block's physical XCD ----
  if (t == 0) {
    int x;
    asm volatile("s_getreg_b32 %0, hwreg(HW_REG_XCC_ID)" : "=s"(x));
    x &= 15;
    s_x  = x;
    s_wi = atomicAdd(&regL[x].v, 1);
  }
  __syncthreads();

  int gen = 0;
  bar_sync(arrGrid, relGrid, NBg, blk, blk == 0, ++gen, true);  // fenced grid bar

  int tot = 0, mn = 1 << 30, mx = 0;
  for (int i = 0; i < 8; ++i) {
    int c = regL[i].v;
    tot += c; mn = min(mn, c); mx = max(mx, c);
  }
  const bool fast = (tot == NBg) && (mn > 0) && (mx <= 256);
  int g, wi, nW;
  if (fast) { g = s_x;     wi = s_wi;     nW = regL[g].v; }
  else      { g = blk & 7; wi = blk >> 3; nW = NBg >> 3;  }
  Line* arr = arrGrpA + g * 256;
  Line* rel = relGrpA + g * 8;
  const bool lead = (wi == 0);

#define GBAR() do { ++gen; if (fast) bar_all(arr, nW, wi, gen); \
                    else bar_sync(arr, rel, nW, wi, lead, gen, true); } while (0)

  // ---- init: rfft along y, 4 x-rows/item packed into 2 complex FFTs ----
  float2* W1 = rec + (size_t)g * (129 * 256);
  for (int w = wi; w < 64; w += nW) {
    const int x0 = w * 4;
#pragma unroll
    for (int p = 0; p < 2; ++p) {
      sh.sAr[p * 256 + t] = vort[((size_t)g * 256 + x0 + 2 * p) * 256 + t];
      sh.sAi[p * 256 + t] = vort[((size_t)g * 256 + x0 + 2 * p + 1) * 256 + t];
    }
    fftB<2, false>(sh, t);
    if (t < 129) {
      int mI = (256 - t) & 255;
#pragma unroll
      for (int p = 0; p < 2; ++p) {
        float zr = sh.sAr[p * 256 + t],  zi = sh.sAi[p * 256 + t];
        float wr = sh.sAr[p * 256 + mI], wi2 = sh.sAi[p * 256 + mI];
        stc(&W1[(size_t)t * 256 + x0 + 2 * p],
            make_float2(0.5f * (zr + wr), 0.5f * (zi - wi2)));
        stc(&W1[(size_t)t * 256 + x0 + 2 * p + 1],
            make_float2(0.5f * (zi + wi2), 0.5f * (wr - zr)));
      }
    }
    __syncthreads();
  }
  GBAR();

  // ---- init: col FFT (W1 -> u) then prepare G; same ky pairs per block ----
  for (int w = wi; w < 43; w += nW) {
    const int ky0 = w * 2;
#pragma unroll
    for (int f = 0; f < 2; ++f) {
      float2 v = ldc(&W1[(size_t)(ky0 + f) * 256 + t]);
      sh.sAr[f * 256 + t] = v.x; sh.sAi[f * 256 + t] = v.y;
    }
    fftB<2, false>(sh, t);
#pragma unroll
    for (int f = 0; f < 2; ++f)
      u[((size_t)g * 129 + ky0 + f) * 256 + t] =
        make_float2(sh.sAr[f * 256 + t], sh.sAi[f * 256 + t]);
  }
  for (int w = wi; w < 43; w += nW)
    spectral_item2(sh, t, g, w * 2, NL1, u, h, G, rec, 0.f, 0.f, 0.f, false, -1);

  // ---- main loop: 90 steps x 5 RK stages ----
  for (int step = 1; step <= 90; ++step) {
    for (int k = 0; k < 5; ++k) {
      GBAR();
      for (int w = wi; w < 64; w += nW)
        real_item4(sh, t, g, w * 4, G, NL1);
      GBAR();
      const int recIdx = (k == 4 && step % 30 == 0) ? (step / 30 - 1) : -1;
      for (int w = wi; w < 43; w += nW)
        spectral_item2(sh, t, g, w * 2, NL1, u, h, G, rec,
                       c_beta[k], c_gdt[k], c_mu[k], true, recIdx);
    }
  }
  GBAR();

  // ---- final: inverse col FFT of records (258 rows, 2 per item) ----
  for (int w = wi; w < 129; w += nW) {
#pragma unroll
    for (int j = 0; j < 2; ++j) {
      int idx = w * 2 + j, r = idx / 86, ky = idx % 86;
      float2 v = ldc(&rec[(((size_t)r * 8 + g) * 129 + ky) * 256 + t]);
      sh.sAr[j * 256 + t] = v.x; sh.sAi[j * 256 + t] = v.y;
    }
    fftB<2, true>(sh, t);
#pragma unroll
    for (int j = 0; j < 2; ++j) {
      int idx = w * 2 + j, r = idx / 86, ky = idx % 86;
      stc(&G[(((size_t)r * 8 + g) * 129 + ky) * 256 + t],
          make_float2(sh.sAr[j * 256 + t], sh.sAi[j * 256 + t]));
    }
  }
  GBAR();

  // ---- final: paired hermitian inverse row FFT -> out (4 cols/item) ----
  const float NRM = 1.0f / 65536.0f;
  for (int w = wi; w < 192; w += nW) {
    const int r = w / 64, xh = w % 64, x0 = xh * 4;
    for (int i = t; i < 516; i += 256) {
      int ky = i >> 2, xl = i & 3;
      float ax = 0.f, ay = 0.f;
      if (ky <= 85) {
        float2 a = ldc(&G[(((size_t)r * 8 + g) * 129 + ky) * 256 + x0 + xl]);
        ax = a.x; ay = a.y;
      }
      sh.t0r[ky * 5 + xl] = ax; sh.t0i[ky * 5 + xl] = ay;
    }
    __syncthreads();
    const int  kk    = (t <= 128) ? t : 256 - t;
    const bool lower = (t <= 128);
#pragma unroll
    for (int f = 0; f < 2; ++f) {
      float ar = sh.t0r[kk * 5 + 2 * f],     ai = sh.t0i[kk * 5 + 2 * f];
      float br = sh.t0r[kk * 5 + 2 * f + 1], bi = sh.t0i[kk * 5 + 2 * f + 1];
      sh.sAr[f * 256 + t] = lower ? (ar - bi) : (ar + bi);
      sh.sAi[f * 256 + t] = lower ? (ai + br) : (br - ai);
    }
    fftB<2, true>(sh, t);
#pragma unroll
    for (int f = 0; f < 2; ++f) {
      out[((((size_t)r * 8 + g) * 256) + x0 + 2 * f) * 256 + t]     = sh.sAr[f * 256 + t] * NRM;
      out[((((size_t)r * 8 + g) * 256) + x0 + 2 * f + 1) * 256 + t] = sh.sAi[f * 256 + t] * NRM;
    }
    __syncthreads();
  }
#undef GBAR
}

// ---------------------------------------------------------------------------
extern "C" void kernel_launch(void* const* d_in, const int* in_sizes, int n_in,
                              void* d_out, int out_size, void* d_ws, size_t ws_size,
                              hipStream_t stream)
{
  const float* vort = (const float*)d_in[0];
  float* out = (float*)d_out;

  float2* base = (float2*)d_ws;
  float2* u    = base;                 // 8*129*256   = 264192
  float2* h    = u + 264192;           // 264192
  float2* G    = h + 264192;           // 4*8*129*256 = 1056768
  float2* NL1  = G + 1056768;          // 8*86*256    = 176128
  float2* rec  = NL1 + 176128;         // 3*8*129*256 = 792576
  Line*   bar  = (Line*)(rec + 792576);
  const int nLines = 1024 + 8 + 2048 + 64 + 16;   // 3160 lines

  hipMemsetAsync(bar, 0, (size_t)nLines * sizeof(Line), stream);

  int maxPerCU = 0;
  hipOccupancyMaxActiveBlocksPerMultiprocessor(&maxPerCU, k_persist, 256, 0);
  int NBg = maxPerCU * 256;            // 256 CUs on MI355X
  if (NBg <= 0)  NBg = 512;
  if (NBg > 512) NBg = 512;            // ~64 blocks/XCD: all busy in real phase
  NBg &= ~63;
  if (NBg < 64)  NBg = 64;

  void* args[] = {(void*)&vort, (void*)&out, (void*)&u, (void*)&h,
                  (void*)&G, (void*)&NL1, (void*)&rec, (void*)&bar};
  hipError_t e = hipLaunchCooperativeKernel(k_persist, dim3(NBg), dim3(256),
                                            args, 0, stream);
  if (e != hipSuccess) {
    hipLaunchKernelGGL(k_persist, dim3(NBg), dim3(256), 0, stream,
                       vort, out, u, h, G, NL1, rec, bar);
  }
}

// Round 8
// 10195.348 us; speedup vs baseline: 1.1407x; 1.1407x over previous
//
#include <hip/hip_runtime.h>
#include <math.h>

#define PI_F 3.14159265358979323846f
typedef unsigned long long u64;

// RK stage constants: beta[k], gdt[k]=GAMMA[k]*DT, mu[k]=0.5*DT*(ALPHA[k+1]-ALPHA[k])
__constant__ float c_beta[5] = {0.0f, -0.4178904745f, -1.192151694643f,
                                -1.697784692471f, -1.514183444257f};
__constant__ float c_gdt[5]  = {1.496590219993e-4f, 3.792103129999e-4f,
                                8.229550293869e-4f, 6.994504559488e-4f,
                                1.530572479681e-4f};
__constant__ float c_mu[5]   = {7.482951099965e-5f, 1.1037096768255e-4f,
                                1.2592740288505e-4f, 1.6801318377015e-4f,
                                2.08589346626e-5f};

struct __align__(128) Line { int v; int pad[31]; };

// Batched FFT workspace: up to 4 transforms side by side.
struct SharedMem {
  float sAr[1024], sAi[1024], sBr[1024], sBi[1024];  // [4][256] ping-pong
  float twr[128], twi[128];
  float t0r[645], t0i[645], t1r[645], t1i[645];      // [129][4] tiles, stride 5
};

// ---------------------------------------------------------------------------
// Handoff data path (intra-XCD producer/consumer through the shared L2):
//   WRITE: plain store — write-through L1 lands it in the XCD's L2 as a
//          dirty write-back line. NO HBM/MALL traffic (this was 6.8 GB/run
//          as agent-scope atomic stores in rounds 6/7).
//   READ : relaxed agent atomic load — bypasses the reader CU's stale L1,
//          hits L2. Generates no write traffic.
// Cross-XCD fallback stays correct via the fenced barrier (wbL2/invL2).
// ---------------------------------------------------------------------------
__device__ __forceinline__ float2 ldc(const float2* p)
{
  u64 v = __hip_atomic_load((const u64*)p, __ATOMIC_RELAXED, __HIP_MEMORY_SCOPE_AGENT);
  float2 f; __builtin_memcpy(&f, &v, 8); return f;
}
__device__ __forceinline__ void stg(float2* p, float2 f)
{
  *p = f;
}

// ---------------------------------------------------------------------------
// Fast group barrier: every block's wave 0 polls ALL n arrival lines
// directly (1/lane, relaxed) — no leader/release round-trip.
// __syncthreads() lowering drains each wave's vmcnt before s_barrier, so all
// plain data stores are in L2 before the arrival flag is stored.
// ---------------------------------------------------------------------------
__device__ __forceinline__ void bar_all(Line* arr, int n, int idx, int gen)
{
  __syncthreads();
  if (threadIdx.x == 0)
    __hip_atomic_store(&arr[idx].v, gen, __ATOMIC_RELAXED, __HIP_MEMORY_SCOPE_AGENT);
  if (threadIdx.x < 64) {
    bool done = false;
    while (!done) {
      bool ok = true;
      for (int w = threadIdx.x; w < n; w += 64)
        if (__hip_atomic_load(&arr[w].v, __ATOMIC_RELAXED, __HIP_MEMORY_SCOPE_AGENT) < gen)
          ok = false;
      done = __all(ok);
      if (!done) __builtin_amdgcn_s_sleep(2);
    }
    __builtin_amdgcn_sched_barrier(0);
  }
  __syncthreads();
}

// Fenced leader-based barrier (registration + cross-XCD fallback path).
// RELEASE flushes dirty L2 (plain stores) to device scope; ACQUIRE invalidates.
__device__ __forceinline__ void bar_sync(Line* arr, Line* rel, int n, int idx,
                                         bool lead, int gen, bool fenced)
{
  const int t = threadIdx.x;
  __syncthreads();
  if (t == 0) {
    __builtin_amdgcn_s_waitcnt(0);
    __builtin_amdgcn_sched_barrier(0);
    if (fenced)
      __hip_atomic_store(&arr[idx].v, gen, __ATOMIC_RELEASE, __HIP_MEMORY_SCOPE_AGENT);
    else
      __hip_atomic_store(&arr[idx].v, gen, __ATOMIC_RELAXED, __HIP_MEMORY_SCOPE_AGENT);
  }
  if (lead && t < 64) {
    bool done = false;
    while (!done) {
      bool ok = true;
      for (int w = t; w < n; w += 64)
        if (__hip_atomic_load(&arr[w].v, __ATOMIC_RELAXED, __HIP_MEMORY_SCOPE_AGENT) < gen)
          ok = false;
      done = __all(ok);
      if (!done) __builtin_amdgcn_s_sleep(1);
    }
    __builtin_amdgcn_sched_barrier(0);
    if (fenced)
      (void)__hip_atomic_load(&arr[t & 7].v, __ATOMIC_ACQUIRE, __HIP_MEMORY_SCOPE_AGENT);
    if (t < 8) {
      if (fenced)
        __hip_atomic_store(&rel[t].v, gen, __ATOMIC_RELEASE, __HIP_MEMORY_SCOPE_AGENT);
      else
        __hip_atomic_store(&rel[t].v, gen, __ATOMIC_RELAXED, __HIP_MEMORY_SCOPE_AGENT);
    }
  }
  if (t == 0) {
    Line* f = &rel[idx & 7];
    while (__hip_atomic_load(&f->v, __ATOMIC_RELAXED, __HIP_MEMORY_SCOPE_AGENT) < gen)
      __builtin_amdgcn_s_sleep(1);
    if (fenced)
      (void)__hip_atomic_load(&f->v, __ATOMIC_ACQUIRE, __HIP_MEMORY_SCOPE_AGENT);
    __builtin_amdgcn_sched_barrier(0);
  }
  __syncthreads();
}

// ---------------------------------------------------------------------------
// Batched 256-point Stockham radix-2 FFT: B transforms side by side in LDS,
// one __syncthreads per stage covers all B. Result ends in sA. No scaling.
// ---------------------------------------------------------------------------
template<int B, bool INVERSE>
__device__ __forceinline__ void fftB(SharedMem& sh, int t)
{
  float *sr = sh.sAr, *si = sh.sAi, *dr = sh.sBr, *di = sh.sBi;
#pragma unroll
  for (int s = 0; s < 8; ++s) {
    __syncthreads();
    int m  = 1 << s;
    int k  = t & (m - 1);
    int jm = (t >> (s + 1)) << s;
    int i0 = k + jm;
    float wr = sh.twr[jm];
    float wi = INVERSE ? -sh.twi[jm] : sh.twi[jm];
    bool odd = (t >> s) & 1;
#pragma unroll
    for (int f = 0; f < B; ++f) {
      float c0r = sr[f * 256 + i0],       c0i = si[f * 256 + i0];
      float c1r = sr[f * 256 + i0 + 128], c1i = si[f * 256 + i0 + 128];
      float orr, oii;
      if (odd) {
        float xr = c0r - c1r, xi = c0i - c1i;
        orr = xr * wr - xi * wi;
        oii = xr * wi + xi * wr;
      } else {
        orr = c0r + c1r;
        oii = c0i + c1i;
      }
      dr[f * 256 + t] = orr; di[f * 256 + t] = oii;
    }
    float* tp;
    tp = sr; sr = dr; dr = tp;
    tp = si; si = di; di = tp;
  }
  __syncthreads();
}

// ---------------------------------------------------------------------------
// Layouts (float2). ky truncated to <=85 (dealias zeroes the rest forever).
//   u, h : [b][ky][kx]     8*129*256   (plain cached: same-block reuse)
//   G    : [f][b][ky][x]   4*8*129*256 (handoff: plain store / ldc load)
//   NL1  : [b][ky][x]      8*86*256    (handoff)
//   rec  : [r][b][ky][kx]  3*8*129*256 (handoff; r=0 slab doubles as W1)
// ---------------------------------------------------------------------------

// real-space item: 4 x-columns. 3 batched FFT passes (4v, 4g, 2fwd).
__device__ __forceinline__ void real_item4(SharedMem& sh, int t, int b, int x0,
    const float2* __restrict__ G, float2* __restrict__ NL1)
{
  for (int i = t; i < 516; i += 256) {               // fields 0,1 tiles
    int ky = i >> 2, xl = i & 3;
    float ax = 0.f, ay = 0.f, cx = 0.f, cy = 0.f;
    if (ky <= 85) {
      float2 a = ldc(&G[(((size_t)0 * 8 + b) * 129 + ky) * 256 + x0 + xl]);
      float2 c = ldc(&G[(((size_t)1 * 8 + b) * 129 + ky) * 256 + x0 + xl]);
      ax = a.x; ay = a.y; cx = c.x; cy = c.y;
    }
    sh.t0r[ky * 5 + xl] = ax; sh.t0i[ky * 5 + xl] = ay;
    sh.t1r[ky * 5 + xl] = cx; sh.t1i[ky * 5 + xl] = cy;
  }
  __syncthreads();
  const int  kk    = (t <= 128) ? t : 256 - t;
  const bool lower = (t <= 128);
#pragma unroll
  for (int xl = 0; xl < 4; ++xl) {                   // Z = Hvx + i*Hvy
    float ar = sh.t0r[kk * 5 + xl], ai = sh.t0i[kk * 5 + xl];
    float br = sh.t1r[kk * 5 + xl], bi = sh.t1i[kk * 5 + xl];
    sh.sAr[xl * 256 + t] = lower ? (ar - bi) : (ar + bi);
    sh.sAi[xl * 256 + t] = lower ? (ai + br) : (br - ai);
  }
  fftB<4, true>(sh, t);
  float vxr[4], vyr[4];
#pragma unroll
  for (int xl = 0; xl < 4; ++xl) { vxr[xl] = sh.sAr[xl * 256 + t]; vyr[xl] = sh.sAi[xl * 256 + t]; }
  for (int i = t; i < 516; i += 256) {               // fields 2,3 tiles
    int ky = i >> 2, xl = i & 3;
    float ax = 0.f, ay = 0.f, cx = 0.f, cy = 0.f;
    if (ky <= 85) {
      float2 a = ldc(&G[(((size_t)2 * 8 + b) * 129 + ky) * 256 + x0 + xl]);
      float2 c = ldc(&G[(((size_t)3 * 8 + b) * 129 + ky) * 256 + x0 + xl]);
      ax = a.x; ay = a.y; cx = c.x; cy = c.y;
    }
    sh.t0r[ky * 5 + xl] = ax; sh.t0i[ky * 5 + xl] = ay;
    sh.t1r[ky * 5 + xl] = cx; sh.t1i[ky * 5 + xl] = cy;
  }
  __syncthreads();
  float nl[4];
#pragma unroll
  for (int xl = 0; xl < 4; ++xl) {                   // Z = Hgx + i*Hgy
    float ar = sh.t0r[kk * 5 + xl], ai = sh.t0i[kk * 5 + xl];
    float br = sh.t1r[kk * 5 + xl], bi = sh.t1i[kk * 5 + xl];
    sh.sAr[xl * 256 + t] = lower ? (ar - bi) : (ar + bi);
    sh.sAi[xl * 256 + t] = lower ? (ai + br) : (br - ai);
  }
  fftB<4, true>(sh, t);
#pragma unroll
  for (int xl = 0; xl < 4; ++xl)
    nl[xl] = -(vxr[xl] * sh.sAr[xl * 256 + t] + vyr[xl] * sh.sAi[xl * 256 + t]);
  // forward rfft of 4 real rows packed into 2 complex FFTs
  sh.sAr[t]       = nl[0]; sh.sAi[t]       = nl[1];
  sh.sAr[256 + t] = nl[2]; sh.sAi[256 + t] = nl[3];
  fftB<2, false>(sh, t);
  if (t <= 85) {
    int mI = (256 - t) & 255;
#pragma unroll
    for (int p = 0; p < 2; ++p) {
      float zr = sh.sAr[p * 256 + t],  zi = sh.sAi[p * 256 + t];
      float wr = sh.sAr[p * 256 + mI], wi = sh.sAi[p * 256 + mI];
      stg(&NL1[((size_t)b * 86 + t) * 256 + x0 + 2 * p],
          make_float2(0.5f * (zr + wr), 0.5f * (zi - wi)));
      stg(&NL1[((size_t)b * 86 + t) * 256 + x0 + 2 * p + 1],
          make_float2(0.5f * (zi + wi), 0.5f * (wr - zr)));
    }
  }
  __syncthreads();   // protect cross-lane sA reads before next item's staging
}

// spectral item: 2 ky rows (ky0, ky0+1; both <86). fwd batch-2 + 2x inverse batch-4.
__device__ __forceinline__ void spectral_item2(SharedMem& sh, int t, int b, int ky0,
    const float2* __restrict__ NL1, float2* __restrict__ u, float2* __restrict__ h,
    float2* __restrict__ G, float2* __restrict__ rec,
    float beta, float gdt, float mu, bool doUpdate, int recIdx)
{
  const int jx = (t < 128) ? t : t - 256;
  const float fjx = (float)jx;
  float ur[2], ui[2];
#pragma unroll
  for (int f = 0; f < 2; ++f) {
    float2 uu = u[((size_t)b * 129 + ky0 + f) * 256 + t];
    ur[f] = uu.x; ui[f] = uu.y;
  }

  if (doUpdate) {
#pragma unroll
    for (int f = 0; f < 2; ++f) {
      float2 nv = ldc(&NL1[((size_t)b * 86 + ky0 + f) * 256 + t]);
      sh.sAr[f * 256 + t] = nv.x; sh.sAi[f * 256 + t] = nv.y;
    }
    fftB<2, false>(sh, t);
#pragma unroll
    for (int f = 0; f < 2; ++f) {
      const int ky = ky0 + f;
      const size_t row = ((size_t)b * 129 + ky) * 256;
      float advr = 0.f, advi = 0.f;
      if (t < 85 || t >= 171) { advr = sh.sAr[f * 256 + t]; advi = sh.sAi[f * 256 + t]; }
      if (t == 0 && ky == 4) {                       // forcing f_hat
        float s_, c_;
        __sincosf(PI_F / 64.0f, &s_, &c_);
        advr -= 131072.0f * c_;
        advi -= 131072.0f * s_;
      }
      float hr = advr, hi = advi;
      if (beta != 0.0f) {
        float2 hh = h[row + t];
        hr += beta * hh.x; hi += beta * hh.y;
      }
      const float k2   = (float)(jx * jx + ky * ky);
      const float lin  = -0.001f * k2 - 0.1f;
      const float anum = 1.0f + mu * lin;
      const float invd = 1.0f / (1.0f - mu * lin);
      ur[f] = (ur[f] * anum + gdt * hr) * invd;
      ui[f] = (ui[f] * anum + gdt * hi) * invd;
      u[row + t] = make_float2(ur[f], ui[f]);
      h[row + t] = make_float2(hr, hi);
      if (recIdx >= 0)
        stg(&rec[((size_t)recIdx * 8 + b) * (129 * 256) + (size_t)ky * 256 + t],
            make_float2(ur[f], ui[f]));
    }
  }

  const float NRM = 1.0f / 65536.0f;
#pragma unroll
  for (int f = 0; f < 2; ++f) {                      // inverse: 4 fields of row f
    const int ky = ky0 + f;
    const float k2 = (float)(jx * jx + ky * ky);
    const float inv_lapnz = (k2 == 0.0f) ? 1.0f : (-1.0f / k2);
    const float urN = ur[f] * NRM, uiN = ui[f] * NRM;
    const float psr = -urN * inv_lapnz, psi_ = -uiN * inv_lapnz;
    const float fjy = (float)ky;
    sh.sAr[0 * 256 + t] = -fjy * psi_; sh.sAi[0 * 256 + t] =  fjy * psr;  // vx
    sh.sAr[1 * 256 + t] =  fjx * psi_; sh.sAi[1 * 256 + t] = -fjx * psr;  // vy
    sh.sAr[2 * 256 + t] = -fjx * uiN;  sh.sAi[2 * 256 + t] =  fjx * urN;  // gx
    sh.sAr[3 * 256 + t] = -fjy * uiN;  sh.sAi[3 * 256 + t] =  fjy * urN;  // gy
    fftB<4, true>(sh, t);
#pragma unroll
    for (int fd = 0; fd < 4; ++fd)
      stg(&G[(((size_t)fd * 8 + b) * 129 + ky) * 256 + t],
          make_float2(sh.sAr[fd * 256 + t], sh.sAi[fd * 256 + t]));
  }
}

// ---------------------------------------------------------------------------
// Persistent kernel. Blocks self-organize into 8 per-XCD groups (HW_REG_XCC_ID);
// group g serves batch g. Fast path: all-poll flag barriers + L2-resident
// handoff. Fallback: blockIdx grouping with fenced leader barriers.
// ---------------------------------------------------------------------------
__global__ __launch_bounds__(256, 4) void k_persist(
    const float* __restrict__ vort, float* __restrict__ out,
    float2* __restrict__ u, float2* __restrict__ h,
    float2* __restrict__ G, float2* __restrict__ NL1, float2* __restrict__ rec,
    Line* __restrict__ bar)
{
  const int t   = threadIdx.x;
  const int blk = blockIdx.x;
  const int NBg = gridDim.x;

  Line* arrGrid = bar;                    // 1024 lines
  Line* relGrid = bar + 1024;             // 8
  Line* arrGrpA = bar + 1032;             // 8 * 256
  Line* relGrpA = bar + 1032 + 2048;      // 8 * 8
  Line* regL    = bar + 1032 + 2048 + 64; // 16: per-XCD counters

  __shared__ SharedMem sh;
  __shared__ int s_x, s_wi;

  if (t < 128) {
    float s_, c_;
    __sincosf(-(2.0f * PI_F / 256.0f) * (float)t, &s_, &c_);
    sh.twr[t] = c_; sh.twi[t] = s_;
  }

  // ---- registration: claim a worker slot on this block's physical XCD ----
  if (t == 0) {
    int x;
    asm volatile("s_getreg_b32 %0, hwreg(HW_REG_XCC_ID)" : "=s"(x));
    x &= 15;
    s_x  = x;
    s_wi = atomicAdd(&regL[x].v, 1);
  }
  __syncthreads();

  int gen = 0;
  bar_sync(arrGrid, relGrid, NBg, blk, blk == 0, ++gen, true);  // fenced grid bar

  int tot = 0, mn = 1 << 30, mx = 0;
  for (int i = 0; i < 8; ++i) {
    int c = regL[i].v;
    tot += c; mn = min(mn, c); mx = max(mx, c);
  }
  const bool fast = (tot == NBg) && (mn > 0) && (mx <= 256);
  int g, wi, nW;
  if (fast) { g = s_x;     wi = s_wi;     nW = regL[g].v; }
  else      { g = blk & 7; wi = blk >> 3; nW = NBg >> 3;  }
  Line* arr = arrGrpA + g * 256;
  Line* rel = relGrpA + g * 8;
  const bool lead = (wi == 0);

#define GBAR() do { ++gen; if (fast) bar_all(arr, nW, wi, gen); \
                    else bar_sync(arr, rel, nW, wi, lead, gen, true); } while (0)

  // ---- init: rfft along y, 4 x-rows/item packed into 2 complex FFTs ----
  float2* W1 = rec + (size_t)g * (129 * 256);
  for (int w = wi; w < 64; w += nW) {
    const int x0 = w * 4;
#pragma unroll
    for (int p = 0; p < 2; ++p) {
      sh.sAr[p * 256 + t] = vort[((size_t)g * 256 + x0 + 2 * p) * 256 + t];
      sh.sAi[p * 256 + t] = vort[((size_t)g * 256 + x0 + 2 * p + 1) * 256 + t];
    }
    fftB<2, false>(sh, t);
    if (t < 129) {
      int mI = (256 - t) & 255;
#pragma unroll
      for (int p = 0; p < 2; ++p) {
        float zr = sh.sAr[p * 256 + t],  zi = sh.sAi[p * 256 + t];
        float wr = sh.sAr[p * 256 + mI], wi2 = sh.sAi[p * 256 + mI];
        stg(&W1[(size_t)t * 256 + x0 + 2 * p],
            make_float2(0.5f * (zr + wr), 0.5f * (zi - wi2)));
        stg(&W1[(size_t)t * 256 + x0 + 2 * p + 1],
            make_float2(0.5f * (zi + wi2), 0.5f * (wr - zr)));
      }
    }
    __syncthreads();
  }
  GBAR();

  // ---- init: col FFT (W1 -> u) then prepare G; same ky pairs per block ----
  for (int w = wi; w < 43; w += nW) {
    const int ky0 = w * 2;
#pragma unroll
    for (int f = 0; f < 2; ++f) {
      float2 v = ldc(&W1[(size_t)(ky0 + f) * 256 + t]);
      sh.sAr[f * 256 + t] = v.x; sh.sAi[f * 256 + t] = v.y;
    }
    fftB<2, false>(sh, t);
#pragma unroll
    for (int f = 0; f < 2; ++f)
      u[((size_t)g * 129 + ky0 + f) * 256 + t] =
        make_float2(sh.sAr[f * 256 + t], sh.sAi[f * 256 + t]);
  }
  for (int w = wi; w < 43; w += nW)
    spectral_item2(sh, t, g, w * 2, NL1, u, h, G, rec, 0.f, 0.f, 0.f, false, -1);

  // ---- main loop: 90 steps x 5 RK stages ----
  for (int step = 1; step <= 90; ++step) {
    for (int k = 0; k < 5; ++k) {
      GBAR();
      for (int w = wi; w < 64; w += nW)
        real_item4(sh, t, g, w * 4, G, NL1);
      GBAR();
      const int recIdx = (k == 4 && step % 30 == 0) ? (step / 30 - 1) : -1;
      for (int w = wi; w < 43; w += nW)
        spectral_item2(sh, t, g, w * 2, NL1, u, h, G, rec,
                       c_beta[k], c_gdt[k], c_mu[k], true, recIdx);
    }
  }
  GBAR();

  // ---- final: inverse col FFT of records (258 rows, 2 per item) ----
  for (int w = wi; w < 129; w += nW) {
#pragma unroll
    for (int j = 0; j < 2; ++j) {
      int idx = w * 2 + j, r = idx / 86, ky = idx % 86;
      float2 v = ldc(&rec[(((size_t)r * 8 + g) * 129 + ky) * 256 + t]);
      sh.sAr[j * 256 + t] = v.x; sh.sAi[j * 256 + t] = v.y;
    }
    fftB<2, true>(sh, t);
#pragma unroll
    for (int j = 0; j < 2; ++j) {
      int idx = w * 2 + j, r = idx / 86, ky = idx % 86;
      stg(&G[(((size_t)r * 8 + g) * 129 + ky) * 256 + t],
          make_float2(sh.sAr[j * 256 + t], sh.sAi[j * 256 + t]));
    }
  }
  GBAR();

  // ---- final: paired hermitian inverse row FFT -> out (4 cols/item) ----
  const float NRM = 1.0f / 65536.0f;
  for (int w = wi; w < 192; w += nW) {
    const int r = w / 64, xh = w % 64, x0 = xh * 4;
    for (int i = t; i < 516; i += 256) {
      int ky = i >> 2, xl = i & 3;
      float ax = 0.f, ay = 0.f;
      if (ky <= 85) {
        float2 a = ldc(&G[(((size_t)r * 8 + g) * 129 + ky) * 256 + x0 + xl]);
        ax = a.x; ay = a.y;
      }
      sh.t0r[ky * 5 + xl] = ax; sh.t0i[ky * 5 + xl] = ay;
    }
    __syncthreads();
    const int  kk    = (t <= 128) ? t : 256 - t;
    const bool lower = (t <= 128);
#pragma unroll
    for (int f = 0; f < 2; ++f) {
      float ar = sh.t0r[kk * 5 + 2 * f],     ai = sh.t0i[kk * 5 + 2 * f];
      float br = sh.t0r[kk * 5 + 2 * f + 1], bi = sh.t0i[kk * 5 + 2 * f + 1];
      sh.sAr[f * 256 + t] = lower ? (ar - bi) : (ar + bi);
      sh.sAi[f * 256 + t] = lower ? (ai + br) : (br - ai);
    }
    fftB<2, true>(sh, t);
#pragma unroll
    for (int f = 0; f < 2; ++f) {
      out[((((size_t)r * 8 + g) * 256) + x0 + 2 * f) * 256 + t]     = sh.sAr[f * 256 + t] * NRM;
      out[((((size_t)r * 8 + g) * 256) + x0 + 2 * f + 1) * 256 + t] = sh.sAi[f * 256 + t] * NRM;
    }
    __syncthreads();
  }
#undef GBAR
}

// ---------------------------------------------------------------------------
extern "C" void kernel_launch(void* const* d_in, const int* in_sizes, int n_in,
                              void* d_out, int out_size, void* d_ws, size_t ws_size,
                              hipStream_t stream)
{
  const float* vort = (const float*)d_in[0];
  float* out = (float*)d_out;

  float2* base = (float2*)d_ws;
  float2* u    = base;                 // 8*129*256   = 264192
  float2* h    = u + 264192;           // 264192
  float2* G    = h + 264192;           // 4*8*129*256 = 1056768
  float2* NL1  = G + 1056768;          // 8*86*256    = 176128
  float2* rec  = NL1 + 176128;         // 3*8*129*256 = 792576
  Line*   bar  = (Line*)(rec + 792576);
  const int nLines = 1024 + 8 + 2048 + 64 + 16;   // 3160 lines

  hipMemsetAsync(bar, 0, (size_t)nLines * sizeof(Line), stream);

  int maxPerCU = 0;
  hipOccupancyMaxActiveBlocksPerMultiprocessor(&maxPerCU, k_persist, 256, 0);
  int NBg = maxPerCU * 256;            // 256 CUs on MI355X
  if (NBg <= 0)  NBg = 512;
  if (NBg > 512) NBg = 512;            // ~64 blocks/XCD: all busy in real phase
  NBg &= ~63;
  if (NBg < 64)  NBg = 64;

  void* args[] = {(void*)&vort, (void*)&out, (void*)&u, (void*)&h,
                  (void*)&G, (void*)&NL1, (void*)&rec, (void*)&bar};
  hipError_t e = hipLaunchCooperativeKernel(k_persist, dim3(NBg), dim3(256),
                                            args, 0, stream);
  if (e != hipSuccess) {
    hipLaunchKernelGGL(k_persist, dim3(NBg), dim3(256), 0, stream,
                       vort, out, u, h, G, NL1, rec, bar);
  }
}